// Round 2
// baseline (150.820 us; speedup 1.0000x reference)
//
#include <hip/hip_runtime.h>

// Guided blur (multichannel guided filter), B=8, C=Cp=3, H=W=512, k=5, eps=1e-4.
// SINGLE fused kernel, LDS-free, barrier-free.
// r14 change (wave-contiguous columns + bpermute shifts + distance-5 prefetch):
//   - r13 post-mortem: removing 3 guidance loads/row was EXACTLY flat (130.2 vs 129.6us,
//     dispatch 60us) -> kernel is VALU-issue bound (VALUBusy 63%), not VMEM-count bound.
//     567 VALU/row measured (0.63*60us -> 22.7k instr/wave), 71 VALU per output pixel.
//   - Old geometry: 4 x 16-lane DPP segments, each 16 raw cols -> 8 outputs (two cascaded
//     5-taps eat 4+4 lanes per segment). 50% lane waste, 2x horizontal load redundancy.
//   - New geometry: ONE contiguous 64-col span per wave. Shifts by +1/+2/+4 lanes cross
//     16-lane rows via ds_bpermute_b32 (LDS crossbar pipe; NOT the r10 wave_shl DPP that
//     regressed 2.2x, and NOT VALU -> shift work moves off the saturated pipe).
//     56 outputs/wave vs 32: VALU/output x0.57, waves 2048 -> 1280, horiz redundancy
//     2.0x -> 1.14x. Wrap garbage from bpermute (lanes >= 56 region) is store-masked.
//   - Occupancy drops to ~1.25 waves/SIMD, so raw-row prefetch deepened 1 -> 5 rows:
//     P[5][6] ring, slot = constexpr I (SROA-safe), consume waits vmcnt(24), never
//     drains; ~2500 cyc issue-to-use covers HBM-miss latency (FETCH shows ~70% of
//     loaded bytes come from HBM).
//   Compile-shape lessons (this session):
//     r5: runtime ring idx -> PromoteAlloca-to-LDS -> 40us LDS-pipe serialization
//     r7: f2 ext-vector arrays in state struct -> failed SROA -> scratch spill (159us)
//     r8: __launch_bounds__(128,4) -> forced 64-VGPR cap -> 440MB spill traffic (213us)
//     r10: wave_shl1 DPP (ctrl 0x130) -> VALUBusy 21%, 160us
//     r9/r11: VALUBusy pinned ~57% at 2 AND 4 waves/SIMD -> per-wave stall, not occupancy
//     r13: removing off-critical-path loads -> exactly neutral
//   Proven safe form: scalar floats, constexpr indices, block=64, __launch_bounds__(64,2).
// No d_ws usage.

namespace {

constexpr int BN = 8;
constexpr int HH = 512;
constexpr int WW = 512;
constexpr int CSZ = HH * WW;
constexpr float GEPS = 1e-4f;
constexpr int OUTW = 56;            // valid output cols per 64-lane wave
constexpr int XBLK = 10;            // ceil(512/56); last block writes 8 cols
constexpr int SR   = 32;            // output rows per wave strip (reads SR+8 raw rows)

__device__ __forceinline__ int refl(int i, int n) {
    // jnp.pad reflect: -1 -> 1, -2 -> 2, n -> n-2, n+1 -> n-3
    if (i < 0) i = -i;
    if (i >= n) i = 2 * n - 2 - i;
    return i;
}

// wave-wide shift-left-by-k via ds_bpermute: lane u receives lane (u+k) & 63.
// idxB = ((lane+k)<<2) precomputed once. Wrap garbage only pollutes lanes >= 60
// -> propagates only into output lanes >= 56, which are store-masked.
__device__ __forceinline__ float shl_b(int idxB, float v) {
    return __builtin_bit_cast(float,
        __builtin_amdgcn_ds_bpermute(idxB, __builtin_bit_cast(int, v)));
}

struct Ctx {
    const float *g0, *g1, *g2, *p0, *p1, *p2;  // channel base pointers
    float *o0, *o1, *o2;
    int yb, xr, xo;
    int i1, i2, i4;                 // bpermute byte indices for +1/+2/+4
    bool wr;
};

// lane u gets v[u]+v[u+1]+v[u+2]+v[u+3]+v[u+4]; valid for u <= 59.
__device__ __forceinline__ float hsum5(const Ctx& cx, float v) {
    float t = v + shl_b(cx.i1, v);
    float q = t + shl_b(cx.i2, t);
    return q + shl_b(cx.i4, v);
}

struct St {
    float P[5][6];     // distance-5 raw-row prefetch ring (slot = rr % 5 = I)
    float V1[21];      // stage-1 vertical window sums (21 stat channels)
    float r1[5][6];    // last 5 raw rows (6 channels)
    float V2[12];      // stage-2 vertical sums of hsum'd a,b
    float r2[5][12];   // last 5 hsum'd a,b rows
};

// One raw row. rr = 5*t + I. All ring slots use constexpr I ((5t+I)%5 == I).
// Consumes St::P[I] (loaded 5 rows ago); if PF, loads row rr+5 into P[I].
// OUT's guidance = ring slot (I+1)%5 (raw row rr-4 == output row), shifted +4 lanes.
template <int I, bool SUB1, bool SOLVE, bool V2SUB, bool OUT, bool PF>
__device__ __forceinline__ void row(St& st, const Ctx& cx, int t) {
    const int rr = 5 * t + I;

    // capture current values from prefetch slot BEFORE refilling it
    float c0 = st.P[I][0], c1 = st.P[I][1], c2 = st.P[I][2];
    float c3 = st.P[I][3], c4 = st.P[I][4], c5 = st.P[I][5];

    if constexpr (PF) {   // row rr+5; first use 5 iterations from now
        const int yn = refl(cx.yb - 4 + rr + 5, HH);
        const int offn = yn * WW + cx.xr;
        st.P[I][0] = cx.g0[offn]; st.P[I][1] = cx.g1[offn]; st.P[I][2] = cx.g2[offn];
        st.P[I][3] = cx.p0[offn]; st.P[I][4] = cx.p1[offn]; st.P[I][5] = cx.p2[offn];
    }

    // add current raw row
    st.V1[0] += c0; st.V1[1] += c1; st.V1[2] += c2;
    st.V1[3] += c3; st.V1[4] += c4; st.V1[5] += c5;
    st.V1[6]  += c0 * c0; st.V1[7]  += c0 * c1; st.V1[8]  += c0 * c2;
    st.V1[9]  += c1 * c1; st.V1[10] += c1 * c2; st.V1[11] += c2 * c2;
    st.V1[12] += c0 * c3; st.V1[13] += c0 * c4; st.V1[14] += c0 * c5;
    st.V1[15] += c1 * c3; st.V1[16] += c1 * c4; st.V1[17] += c1 * c5;
    st.V1[18] += c2 * c3; st.V1[19] += c2 * c4; st.V1[20] += c2 * c5;

    if constexpr (SUB1) {   // drop raw row rr-5 (same constexpr slot I)
        float o0 = st.r1[I][0], o1 = st.r1[I][1], o2 = st.r1[I][2];
        float o3 = st.r1[I][3], o4 = st.r1[I][4], o5 = st.r1[I][5];
        st.V1[0] -= o0; st.V1[1] -= o1; st.V1[2] -= o2;
        st.V1[3] -= o3; st.V1[4] -= o4; st.V1[5] -= o5;
        st.V1[6]  -= o0 * o0; st.V1[7]  -= o0 * o1; st.V1[8]  -= o0 * o2;
        st.V1[9]  -= o1 * o1; st.V1[10] -= o1 * o2; st.V1[11] -= o2 * o2;
        st.V1[12] -= o0 * o3; st.V1[13] -= o0 * o4; st.V1[14] -= o0 * o5;
        st.V1[15] -= o1 * o3; st.V1[16] -= o1 * o4; st.V1[17] -= o1 * o5;
        st.V1[18] -= o2 * o3; st.V1[19] -= o2 * o4; st.V1[20] -= o2 * o5;
    }
    st.r1[I][0] = c0; st.r1[I][1] = c1; st.r1[I][2] = c2;
    st.r1[I][3] = c3; st.r1[I][4] = c4; st.r1[I][5] = c5;

    if constexpr (SOLVE) {
        // ---- stage 1 finalize: a-col at lane u = xob + u - 2 ----
        float S[21];
#pragma unroll
        for (int c = 0; c < 21; ++c) S[c] = hsum5(cx, st.V1[c]);

        const float nrm = 0.04f;  // 1/25
        float mI0 = S[0] * nrm, mI1 = S[1] * nrm, mI2 = S[2] * nrm;
        float mP0 = S[3] * nrm, mP1 = S[4] * nrm, mP2 = S[5] * nrm;
        float v00 = S[6]  * nrm - mI0 * mI0 + GEPS;
        float v01 = S[7]  * nrm - mI0 * mI1;
        float v02 = S[8]  * nrm - mI0 * mI2;
        float v11 = S[9]  * nrm - mI1 * mI1 + GEPS;
        float v12 = S[10] * nrm - mI1 * mI2;
        float v22 = S[11] * nrm - mI2 * mI2 + GEPS;
        float c00 = S[12] * nrm - mI0 * mP0;
        float c01 = S[13] * nrm - mI0 * mP1;
        float c02 = S[14] * nrm - mI0 * mP2;
        float c10 = S[15] * nrm - mI1 * mP0;
        float c11 = S[16] * nrm - mI1 * mP1;
        float c12 = S[17] * nrm - mI1 * mP2;
        float c20 = S[18] * nrm - mI2 * mP0;
        float c21 = S[19] * nrm - mI2 * mP1;
        float c22 = S[20] * nrm - mI2 * mP2;
        // symmetric 3x3 inverse via adjugate (A PD: PSD + eps*I)
        float i00 = v11 * v22 - v12 * v12;
        float i01 = v02 * v12 - v01 * v22;
        float i02 = v01 * v12 - v02 * v11;
        float i11 = v00 * v22 - v02 * v02;
        float i12 = v01 * v02 - v00 * v12;
        float i22 = v00 * v11 - v01 * v01;
        float det = v00 * i00 + v01 * i01 + v02 * i02;
        float rd  = __builtin_amdgcn_rcpf(det);   // ~1e-7 rel err, fine vs 0.019 threshold
        float a00 = (i00 * c00 + i01 * c10 + i02 * c20) * rd;
        float a01 = (i00 * c01 + i01 * c11 + i02 * c21) * rd;
        float a02 = (i00 * c02 + i01 * c12 + i02 * c22) * rd;
        float a10 = (i01 * c00 + i11 * c10 + i12 * c20) * rd;
        float a11 = (i01 * c01 + i11 * c11 + i12 * c21) * rd;
        float a12 = (i01 * c02 + i11 * c12 + i12 * c22) * rd;
        float a20 = (i02 * c00 + i12 * c10 + i22 * c20) * rd;
        float a21 = (i02 * c01 + i12 * c11 + i22 * c21) * rd;
        float a22 = (i02 * c02 + i12 * c12 + i22 * c22) * rd;
        float b0 = mP0 - (a00 * mI0 + a10 * mI1 + a20 * mI2);
        float b1 = mP1 - (a01 * mI0 + a11 * mI1 + a21 * mI2);
        float b2 = mP2 - (a02 * mI0 + a12 * mI1 + a22 * mI2);

        // ---- stage 2: horizontal 5-tap of a,b now; vertical roll ----
        float hv[12];
        hv[0] = hsum5(cx, a00); hv[1]  = hsum5(cx, a01); hv[2]  = hsum5(cx, a02);
        hv[3] = hsum5(cx, a10); hv[4]  = hsum5(cx, a11); hv[5]  = hsum5(cx, a12);
        hv[6] = hsum5(cx, a20); hv[7]  = hsum5(cx, a21); hv[8]  = hsum5(cx, a22);
        hv[9] = hsum5(cx, b0);  hv[10] = hsum5(cx, b1);  hv[11] = hsum5(cx, b2);

#pragma unroll
        for (int c = 0; c < 12; ++c) {
            st.V2[c] += hv[c];
            if constexpr (V2SUB) st.V2[c] -= st.r2[I][c];  // read old before overwrite
            st.r2[I][c] = hv[c];
        }

        if constexpr (OUT) {
            // output row yo = yb + rr - 8 == raw row rr-4 (interior, refl identity),
            // live in ring slot J=(I+1)%5. Output col xob+u = raw col of lane u+4
            // -> shift ring guidance left by 4 lanes (reuse i4 bpermute index).
            constexpr int J = (I + 1) % 5;
            float gg0 = shl_b(cx.i4, st.r1[J][0]);
            float gg1 = shl_b(cx.i4, st.r1[J][1]);
            float gg2 = shl_b(cx.i4, st.r1[J][2]);
            const int oOff = (cx.yb + rr - 8) * WW + cx.xo;
            // mean = V2 / 25
            float M[12];
#pragma unroll
            for (int c = 0; c < 12; ++c) M[c] = st.V2[c] * 0.04f;
            float o0 = gg0 * M[0] + gg1 * M[3] + gg2 * M[6] + M[9];
            float o1 = gg0 * M[1] + gg1 * M[4] + gg2 * M[7] + M[10];
            float o2 = gg0 * M[2] + gg1 * M[5] + gg2 * M[8] + M[11];
            if (cx.wr) {
                cx.o0[oOff] = o0;
                cx.o1[oOff] = o1;
                cx.o2[oOff] = o2;
            }
        }
    }
}

__global__ __launch_bounds__(64, 2) void fused_kernel(
        const float* __restrict__ g, const float* __restrict__ p,
        float* __restrict__ out) {
    const int lane = threadIdx.x;       // 64 threads = 1 wave, contiguous 64-col span
    const int bb   = blockIdx.z;
    const int xob  = blockIdx.x * OUTW; // output col base

    const int xq = xob - 4 + lane;      // raw read col (pre-reflect)

    Ctx cx;
    cx.g0 = g + (size_t)bb * 3 * CSZ; cx.g1 = cx.g0 + CSZ; cx.g2 = cx.g0 + 2 * CSZ;
    cx.p0 = p + (size_t)bb * 3 * CSZ; cx.p1 = cx.p0 + CSZ; cx.p2 = cx.p0 + 2 * CSZ;
    cx.o0 = out + (size_t)bb * 3 * CSZ; cx.o1 = cx.o0 + CSZ; cx.o2 = cx.o0 + 2 * CSZ;
    cx.yb = blockIdx.y * SR;
    cx.xr = refl(xq, WW);
    cx.xo = xob + lane;                 // may exceed 511 only on masked lanes
    cx.wr = (lane < OUTW) && (cx.xo < WW);
    cx.i1 = (lane + 1) << 2;
    cx.i2 = (lane + 2) << 2;
    cx.i4 = (lane + 4) << 2;

    St st;
#pragma unroll
    for (int i = 0; i < 21; ++i) st.V1[i] = 0.f;
#pragma unroll
    for (int i = 0; i < 12; ++i) st.V2[i] = 0.f;

    // prime the prefetch ring with raw rows 0..4
#pragma unroll
    for (int j = 0; j < 5; ++j) {
        const int y0 = refl(cx.yb - 4 + j, HH);
        const int off0 = y0 * WW + cx.xr;
        st.P[j][0] = cx.g0[off0]; st.P[j][1] = cx.g1[off0]; st.P[j][2] = cx.g2[off0];
        st.P[j][3] = cx.p0[off0]; st.P[j][4] = cx.p1[off0]; st.P[j][5] = cx.p2[off0];
    }

    // 40 raw rows total (rr = 0..39); outputs at rr = 8..39 -> rows yb..yb+31.
    // PF (load row rr+5 into slot I) active for rr <= 34 (trips 0..6).
    // trip 0: rows 0..4 — accumulate; first solve at rr=4
    row<0, false, false, false, false, true>(st, cx, 0);
    row<1, false, false, false, false, true>(st, cx, 0);
    row<2, false, false, false, false, true>(st, cx, 0);
    row<3, false, false, false, false, true>(st, cx, 0);
    row<4, false, true,  false, false, true>(st, cx, 0);
    // trip 1: rows 5..9 — first outputs at rr=8,9; first V2-sub at rr=9
    row<0, true, true, false, false, true>(st, cx, 1);
    row<1, true, true, false, false, true>(st, cx, 1);
    row<2, true, true, false, false, true>(st, cx, 1);
    row<3, true, true, false, true,  true>(st, cx, 1);
    row<4, true, true, true,  true,  true>(st, cx, 1);
    // steady trips: rows 10..34
#pragma unroll 1
    for (int t = 2; t <= 6; ++t) {
        row<0, true, true, true, true, true>(st, cx, t);
        row<1, true, true, true, true, true>(st, cx, t);
        row<2, true, true, true, true, true>(st, cx, t);
        row<3, true, true, true, true, true>(st, cx, t);
        row<4, true, true, true, true, true>(st, cx, t);
    }
    // tail trip 7: rows 35..39 (prefetch ring already holds them; no more loads)
    row<0, true, true, true, true, false>(st, cx, 7);
    row<1, true, true, true, true, false>(st, cx, 7);
    row<2, true, true, true, true, false>(st, cx, 7);
    row<3, true, true, true, true, false>(st, cx, 7);
    row<4, true, true, true, true, false>(st, cx, 7);
}

}  // namespace

extern "C" void kernel_launch(void* const* d_in, const int* in_sizes, int n_in,
                              void* d_out, int out_size, void* d_ws, size_t ws_size,
                              hipStream_t stream) {
    const float* g  = (const float*)d_in[0];   // guidance [8,3,512,512]
    const float* p  = (const float*)d_in[1];   // input    [8,3,512,512]
    float* out = (float*)d_out;                // [8,3,512,512]

    dim3 grid(XBLK, HH / SR, BN);              // (10, 16, 8) = 1280 single-wave blocks
    dim3 block(64);

    hipLaunchKernelGGL(fused_kernel, grid, block, 0, stream, g, p, out);
}

// Round 7
// 136.637 us; speedup vs baseline: 1.1038x; 1.1038x over previous
//
#include <hip/hip_runtime.h>

// Guided blur (multichannel guided filter), B=8, C=Cp=3, H=W=512, k=5, eps=1e-4.
// SINGLE fused kernel, LDS-free, barrier-free, 16-lane-row DPP horizontal taps,
// 6-load distance-1 software pipeline, guidance-from-ring (r13 geometry, 60us).
// r15 change (code-size collapse -> fit L1I):
//   - r14 post-mortem: wave-contiguous bpermute shifts -> VALUBusy 24%, 80us. The
//     ds_bpermute dependent chains (3 serial LDS-crossbar round-trips per hsum5, 33
//     hsum5/row) are latency-bound at ~1.25 waves/SIMD. DPP-folded-into-VALU is the
//     only cheap shift here. Geometry reverted to r13's 4x16-lane segments.
//   - r13/r9/r11 anomaly set: VALUBusy pinned ~60% at BOTH 2 and 4 waves/SIMD, and
//     neutral to removing loads -> stalls that extra waves don't fill = SHARED resource
//     = L1 instruction cache. Unique static code was ~90KB (trips 0,1,7 unrolled + steady
//     body, 567 VALU/row measured) vs 32KB L1I shared per CU cluster.
//   - Fix: ONE loop body for all 8 trips; SUB1/SOLVE/V2SUB/OUT become runtime
//     wave-uniform scalar branches (rr>=5/4/9/8); PF unconditional (row-40 prefetch
//     reflects to row 506, in-bounds, result unused -> harmless). Ring indices REMAIN
//     template<int I> constexpr (r5 lesson: runtime ring idx -> LDS promotion disaster).
//     Opaque asm on trip base prevents loop-peeling from re-specializing t=0.
//     Static code ~25KB -> fits I$.
//   Compile-shape lessons (this session):
//     r5: runtime ring idx -> PromoteAlloca-to-LDS -> 40us LDS-pipe serialization
//     r7: f2 ext-vector arrays in state struct -> failed SROA -> scratch spill (159us)
//     r8: __launch_bounds__(128,4) -> forced 64-VGPR cap -> 440MB spill traffic (213us)
//     r10: wave_shl1 DPP (ctrl 0x130) -> VALUBusy 21%, 160us
//     r14: ds_bpermute hsum5 chains -> VALUBusy 24%, 80us
//     r13: removing off-critical-path loads -> exactly neutral
//   Proven safe form: scalar floats, constexpr ring indices, block=64,
//   __launch_bounds__(64,2), SR=32 geometry.
// No d_ws usage.

namespace {

constexpr int BN = 8;
constexpr int HH = 512;
constexpr int WW = 512;
constexpr int CSZ = HH * WW;
constexpr float GEPS = 1e-4f;
constexpr int SEGW = 8;             // output cols per 16-lane segment
constexpr int OUTW = 4 * SEGW;      // 32 output cols per wave
constexpr int SR   = 32;            // output rows per wave strip (reads SR+8 raw rows)

__device__ __forceinline__ int refl(int i, int n) {
    // jnp.pad reflect: -1 -> 1, -2 -> 2, n -> n-2, n+1 -> n-3
    if (i < 0) i = -i;
    if (i >= n) i = 2 * n - 2 - i;
    return i;
}

// DPP row_shl:N within each 16-lane row: lane u receives lane u+N (0 past row end).
template <int N>
__device__ __forceinline__ float shlN(float v) {
    return __builtin_bit_cast(float,
        __builtin_amdgcn_update_dpp(0, __builtin_bit_cast(int, v),
                                    0x100 + N, 0xF, 0xF, true));
}
// row-local lane u gets v[u]+v[u+1]+v[u+2]+v[u+3]+v[u+4]; valid for u <= 11.
__device__ __forceinline__ float hsum5(float v) {
    float t = v + shlN<1>(v);
    float q = t + shlN<2>(t);
    return q + shlN<4>(v);
}

struct St {
    float P[6];        // prefetched next raw row (6 channels)
    float V1[21];      // stage-1 vertical window sums (21 stat channels)
    float r1[5][6];    // last 5 raw rows (6 channels)
    float V2[12];      // stage-2 vertical sums of hsum'd a,b
    float r2[5][12];   // last 5 hsum'd a,b rows
};

struct Ctx {
    const float *g0, *g1, *g2, *p0, *p1, *p2;  // channel base pointers
    float *o0, *o1, *o2;
    int yb, xr, xs;
    bool wr;
};

// One raw row. rr = rrb + I (rrb = 5*t, runtime-opaque). Ring slots use constexpr I
// ((5t+I)%5 == I). Feature gating is RUNTIME wave-uniform (scalar branches):
//   SUB1: rr>=5, SOLVE: rr>=4, V2SUB: rr>=9, OUT: rr>=8; PF unconditional.
// Consumes St::P (prefetched last row). OUT's guidance = ring slot (I+1)%5
// (raw row rr-4 == output row, interior so refl was identity), shifted +4 lanes.
template <int I>
__device__ __forceinline__ void row(St& st, const Ctx& cx, int rrb) {
    const int rr = rrb + I;

    // capture current values from prefetch buffer BEFORE overwriting it
    float c0 = st.P[0], c1 = st.P[1], c2 = st.P[2];
    float c3 = st.P[3], c4 = st.P[4], c5 = st.P[5];

    {   // prefetch next raw row; first use is next row. Always valid post-refl.
        const int yn = refl(cx.yb - 4 + rr + 1, HH);
        const int offn = yn * WW + cx.xr;
        st.P[0] = cx.g0[offn]; st.P[1] = cx.g1[offn]; st.P[2] = cx.g2[offn];
        st.P[3] = cx.p0[offn]; st.P[4] = cx.p1[offn]; st.P[5] = cx.p2[offn];
    }

    // add current raw row
    st.V1[0] += c0; st.V1[1] += c1; st.V1[2] += c2;
    st.V1[3] += c3; st.V1[4] += c4; st.V1[5] += c5;
    st.V1[6]  += c0 * c0; st.V1[7]  += c0 * c1; st.V1[8]  += c0 * c2;
    st.V1[9]  += c1 * c1; st.V1[10] += c1 * c2; st.V1[11] += c2 * c2;
    st.V1[12] += c0 * c3; st.V1[13] += c0 * c4; st.V1[14] += c0 * c5;
    st.V1[15] += c1 * c3; st.V1[16] += c1 * c4; st.V1[17] += c1 * c5;
    st.V1[18] += c2 * c3; st.V1[19] += c2 * c4; st.V1[20] += c2 * c5;

    if (rr >= 5) {   // drop raw row rr-5 (same constexpr slot I)
        float o0 = st.r1[I][0], o1 = st.r1[I][1], o2 = st.r1[I][2];
        float o3 = st.r1[I][3], o4 = st.r1[I][4], o5 = st.r1[I][5];
        st.V1[0] -= o0; st.V1[1] -= o1; st.V1[2] -= o2;
        st.V1[3] -= o3; st.V1[4] -= o4; st.V1[5] -= o5;
        st.V1[6]  -= o0 * o0; st.V1[7]  -= o0 * o1; st.V1[8]  -= o0 * o2;
        st.V1[9]  -= o1 * o1; st.V1[10] -= o1 * o2; st.V1[11] -= o2 * o2;
        st.V1[12] -= o0 * o3; st.V1[13] -= o0 * o4; st.V1[14] -= o0 * o5;
        st.V1[15] -= o1 * o3; st.V1[16] -= o1 * o4; st.V1[17] -= o1 * o5;
        st.V1[18] -= o2 * o3; st.V1[19] -= o2 * o4; st.V1[20] -= o2 * o5;
    }
    st.r1[I][0] = c0; st.r1[I][1] = c1; st.r1[I][2] = c2;
    st.r1[I][3] = c3; st.r1[I][4] = c4; st.r1[I][5] = c5;

    if (rr >= 4) {
        // ---- stage 1 finalize: a-row at y = yb + rr - 6, a-col xbase+l ----
        float S[21];
#pragma unroll
        for (int c = 0; c < 21; ++c) S[c] = hsum5(st.V1[c]);

        const float nrm = 0.04f;  // 1/25
        float mI0 = S[0] * nrm, mI1 = S[1] * nrm, mI2 = S[2] * nrm;
        float mP0 = S[3] * nrm, mP1 = S[4] * nrm, mP2 = S[5] * nrm;
        float v00 = S[6]  * nrm - mI0 * mI0 + GEPS;
        float v01 = S[7]  * nrm - mI0 * mI1;
        float v02 = S[8]  * nrm - mI0 * mI2;
        float v11 = S[9]  * nrm - mI1 * mI1 + GEPS;
        float v12 = S[10] * nrm - mI1 * mI2;
        float v22 = S[11] * nrm - mI2 * mI2 + GEPS;
        float c00 = S[12] * nrm - mI0 * mP0;
        float c01 = S[13] * nrm - mI0 * mP1;
        float c02 = S[14] * nrm - mI0 * mP2;
        float c10 = S[15] * nrm - mI1 * mP0;
        float c11 = S[16] * nrm - mI1 * mP1;
        float c12 = S[17] * nrm - mI1 * mP2;
        float c20 = S[18] * nrm - mI2 * mP0;
        float c21 = S[19] * nrm - mI2 * mP1;
        float c22 = S[20] * nrm - mI2 * mP2;
        // symmetric 3x3 inverse via adjugate (A PD: PSD + eps*I)
        float i00 = v11 * v22 - v12 * v12;
        float i01 = v02 * v12 - v01 * v22;
        float i02 = v01 * v12 - v02 * v11;
        float i11 = v00 * v22 - v02 * v02;
        float i12 = v01 * v02 - v00 * v12;
        float i22 = v00 * v11 - v01 * v01;
        float det = v00 * i00 + v01 * i01 + v02 * i02;
        float rd  = __builtin_amdgcn_rcpf(det);   // ~1e-7 rel err, fine vs 0.019 threshold
        float a00 = (i00 * c00 + i01 * c10 + i02 * c20) * rd;
        float a01 = (i00 * c01 + i01 * c11 + i02 * c21) * rd;
        float a02 = (i00 * c02 + i01 * c12 + i02 * c22) * rd;
        float a10 = (i01 * c00 + i11 * c10 + i12 * c20) * rd;
        float a11 = (i01 * c01 + i11 * c11 + i12 * c21) * rd;
        float a12 = (i01 * c02 + i11 * c12 + i12 * c22) * rd;
        float a20 = (i02 * c00 + i12 * c10 + i22 * c20) * rd;
        float a21 = (i02 * c01 + i12 * c11 + i22 * c21) * rd;
        float a22 = (i02 * c02 + i12 * c12 + i22 * c22) * rd;
        float b0 = mP0 - (a00 * mI0 + a10 * mI1 + a20 * mI2);
        float b1 = mP1 - (a01 * mI0 + a11 * mI1 + a21 * mI2);
        float b2 = mP2 - (a02 * mI0 + a12 * mI1 + a22 * mI2);

        // ---- stage 2: horizontal 5-tap of a,b now; vertical roll ----
        float hv[12];
        hv[0] = hsum5(a00); hv[1]  = hsum5(a01); hv[2]  = hsum5(a02);
        hv[3] = hsum5(a10); hv[4]  = hsum5(a11); hv[5]  = hsum5(a12);
        hv[6] = hsum5(a20); hv[7]  = hsum5(a21); hv[8]  = hsum5(a22);
        hv[9] = hsum5(b0);  hv[10] = hsum5(b1);  hv[11] = hsum5(b2);

        if (rr >= 9) {
#pragma unroll
            for (int c = 0; c < 12; ++c) {
                st.V2[c] += hv[c] - st.r2[I][c];   // read old before overwrite
                st.r2[I][c] = hv[c];
            }
        } else {
#pragma unroll
            for (int c = 0; c < 12; ++c) {
                st.V2[c] += hv[c];
                st.r2[I][c] = hv[c];
            }
        }

        if (rr >= 8) {
            // output row yo = yb + rr - 8 == raw row rr-4 (interior, refl identity),
            // live in ring slot J=(I+1)%5. Needed col xbase+l+2 = raw col of lane l+4
            // (in-bounds for valid outputs, so refl identity). row_shl:4 stays within
            // the 16-lane segment; lanes l>=8 get garbage/0 but have wr==false.
            constexpr int J = (I + 1) % 5;
            float gg0 = shlN<4>(st.r1[J][0]);
            float gg1 = shlN<4>(st.r1[J][1]);
            float gg2 = shlN<4>(st.r1[J][2]);
            const int oOff = (cx.yb + rr - 8) * WW + cx.xs;
            // mean = V2 / 25
            float M[12];
#pragma unroll
            for (int c = 0; c < 12; ++c) M[c] = st.V2[c] * 0.04f;
            float o0 = gg0 * M[0] + gg1 * M[3] + gg2 * M[6] + M[9];
            float o1 = gg0 * M[1] + gg1 * M[4] + gg2 * M[7] + M[10];
            float o2 = gg0 * M[2] + gg1 * M[5] + gg2 * M[8] + M[11];
            if (cx.wr) {
                cx.o0[oOff] = o0;
                cx.o1[oOff] = o1;
                cx.o2[oOff] = o2;
            }
        }
    }
}

__global__ __launch_bounds__(64, 2) void fused_kernel(
        const float* __restrict__ g, const float* __restrict__ p,
        float* __restrict__ out) {
    const int lane = threadIdx.x;       // 64 threads = 1 wave
    const int l    = lane & 15;
    const int seg  = lane >> 4;
    const int XO   = blockIdx.x * OUTW;
    const int bb   = blockIdx.z;

    const int xbase = XO + seg * SEGW - 2;          // a-col of row-local lane 0
    const int xrq   = xbase + l - 2;                // raw read col (pre-reflect)
    const int xo    = xbase + l + 2;                // output col (valid l < SEGW)

    Ctx cx;
    cx.g0 = g + (size_t)bb * 3 * CSZ; cx.g1 = cx.g0 + CSZ; cx.g2 = cx.g0 + 2 * CSZ;
    cx.p0 = p + (size_t)bb * 3 * CSZ; cx.p1 = cx.p0 + CSZ; cx.p2 = cx.p0 + 2 * CSZ;
    cx.o0 = out + (size_t)bb * 3 * CSZ; cx.o1 = cx.o0 + CSZ; cx.o2 = cx.o0 + 2 * CSZ;
    cx.yb = blockIdx.y * SR;
    cx.xr = refl(xrq, WW);
    cx.xs = (xo < WW) ? xo : (WW - 1);
    cx.wr = (l < SEGW);                             // xo < 512 guaranteed for l < SEGW

    St st;
#pragma unroll
    for (int i = 0; i < 21; ++i) st.V1[i] = 0.f;
#pragma unroll
    for (int i = 0; i < 12; ++i) st.V2[i] = 0.f;
    // r2 slots are write-before-read (first V2SUB at rr=9 reads slot written at rr=4);
    // r1 slots are write-before-read (first SUB1 at rr=5 reads slot written at rr=0).

    // prime the prefetch buffer with raw row 0
    {
        const int y0 = refl(cx.yb - 4, HH);
        const int off0 = y0 * WW + cx.xr;
        st.P[0] = cx.g0[off0]; st.P[1] = cx.g1[off0]; st.P[2] = cx.g2[off0];
        st.P[3] = cx.p0[off0]; st.P[4] = cx.p1[off0]; st.P[5] = cx.p2[off0];
    }

    // 40 raw rows (rr = 0..39) in 8 trips of 5; outputs at rr = 8..39 -> rows yb..yb+31.
    // ONE loop body for all trips (I$ fit); feature flags are runtime scalar branches.
#pragma unroll 1
    for (int t = 0; t < 8; ++t) {
        int rrb = 5 * t;
        // opaque: block loop-peeling from re-specializing early trips back into
        // straight-line code (which is what blew past the 32KB L1I).
        asm("" : "+s"(rrb));
        row<0>(st, cx, rrb);
        row<1>(st, cx, rrb);
        row<2>(st, cx, rrb);
        row<3>(st, cx, rrb);
        row<4>(st, cx, rrb);
    }
}

}  // namespace

extern "C" void kernel_launch(void* const* d_in, const int* in_sizes, int n_in,
                              void* d_out, int out_size, void* d_ws, size_t ws_size,
                              hipStream_t stream) {
    const float* g  = (const float*)d_in[0];   // guidance [8,3,512,512]
    const float* p  = (const float*)d_in[1];   // input    [8,3,512,512]
    float* out = (float*)d_out;                // [8,3,512,512]

    dim3 grid(WW / OUTW, HH / SR, BN);         // (16, 16, 8) = 2048 single-wave blocks
    dim3 block(64);

    hipLaunchKernelGGL(fused_kernel, grid, block, 0, stream, g, p, out);
}

// Round 8
// 132.098 us; speedup vs baseline: 1.1417x; 1.0344x over previous
//
#include <hip/hip_runtime.h>

// Guided blur (multichannel guided filter), B=8, C=Cp=3, H=W=512, k=5, eps=1e-4.
// SINGLE fused kernel, LDS-free, barrier-free, 16-lane-row DPP horizontal taps,
// 6-load distance-1 software pipeline, guidance-from-ring.
// r16 change (explicit 1-row stage pipeline):
//   - r15 post-mortem: rolled 1-row body w/ runtime flag BRANCHES -> 91us, VALUBusy 46.7%
//     (vs r13 60us/63%). VALU work only +12%; stall time 22->48us. The CFG splits
//     (~8 tiny blocks/row) killed cross-row scheduling + waitcnt placement. NOTE:
//     r13's steady phase was ALREADY a rolled 5-row single-block body at 60us -> I$
//     footprint was never dominant; SCHEDULING REGION SIZE is. Lesson: constexpr-flag
//     specialized bodies in big blocks = fast; runtime-branch bodies = -50%.
//   - r13 residual: 37% VALU-idle, insensitive to occupancy (r9/r11) and load removal
//     (r13) -> per-wave dependency-chain stalls. Each row = ONE serial chain:
//     loads -> V1 roll -> 21 chained-DPP hsum5 -> serial 3x3 solve -> 12 hsum5 -> out.
//   - Fix: lag stage-2 by one row. Iteration rr runs stage2(solve of rr-1) then
//     stage1(row rr) in the same block: two INDEPENDENT ~180-op chains adjacent ->
//     scheduler fills each chain's DPP-hazard/latency bubbles with the other's ops.
//     Carries a,b (12 VGPRs) across iterations. Same arithmetic per output as r13.
//   - Index map (verified): iteration rr: stage2 consumes A=solve(rr-1) (a-row
//     yb+rr-7), output row yo=yb+rr-9 == raw row rr-5 == ring slot I=rr%5 (read
//     BEFORE stage1 overwrites it; SUB1 reads the same slot). OUT at rr>=9,
//     V2SUB at rr>=10 (r2[I] last written rr-5). Epilogue rr=40: stage2 only.
//   Compile-shape lessons (this session):
//     r5: runtime ring idx -> PromoteAlloca-to-LDS -> 40us LDS-pipe serialization
//     r7: f2 ext-vector arrays in state struct -> failed SROA -> scratch spill (159us)
//     r8: __launch_bounds__(128,4) -> forced 64-VGPR cap -> 440MB spill traffic (213us)
//     r10: wave_shl1 DPP (ctrl 0x130) -> VALUBusy 21%, 160us
//     r14: ds_bpermute hsum5 chains at 1.25 waves/SIMD -> latency-bound, 80us
//     r15: runtime-branch rolled body -> CFG-split scheduling collapse, 91us
//   Proven safe form: scalar floats, constexpr ring indices, block=64,
//   __launch_bounds__(64,2), SR=32 geometry, 5-row single-block trip bodies.
// No d_ws usage.

namespace {

constexpr int BN = 8;
constexpr int HH = 512;
constexpr int WW = 512;
constexpr int CSZ = HH * WW;
constexpr float GEPS = 1e-4f;
constexpr int SEGW = 8;             // output cols per 16-lane segment
constexpr int OUTW = 4 * SEGW;      // 32 output cols per wave
constexpr int SR   = 32;            // output rows per wave strip (reads SR+8 raw rows)

__device__ __forceinline__ int refl(int i, int n) {
    // jnp.pad reflect: -1 -> 1, -2 -> 2, n -> n-2, n+1 -> n-3
    if (i < 0) i = -i;
    if (i >= n) i = 2 * n - 2 - i;
    return i;
}

// DPP row_shl:N within each 16-lane row: lane u receives lane u+N (0 past row end).
template <int N>
__device__ __forceinline__ float shlN(float v) {
    return __builtin_bit_cast(float,
        __builtin_amdgcn_update_dpp(0, __builtin_bit_cast(int, v),
                                    0x100 + N, 0xF, 0xF, true));
}
// row-local lane u gets v[u]+v[u+1]+v[u+2]+v[u+3]+v[u+4]; valid for u <= 11.
__device__ __forceinline__ float hsum5(float v) {
    float t = v + shlN<1>(v);
    float q = t + shlN<2>(t);
    return q + shlN<4>(v);
}

struct St {
    float P[6];        // prefetched next raw row (6 channels)
    float V1[21];      // stage-1 vertical window sums (21 stat channels)
    float r1[5][6];    // last 5 raw rows (6 channels)
    float V2[12];      // stage-2 vertical sums of hsum'd a,b
    float r2[5][12];   // last 5 hsum'd a,b rows
    float A[12];       // pipeline reg: a00..a22,b0..b2 from PREVIOUS iteration's solve
};

struct Ctx {
    const float *g0, *g1, *g2, *p0, *p1, *p2;  // channel base pointers
    float *o0, *o1, *o2;
    int yb, xr, xs;
    bool wr;
};

// Stage 2 of iteration rr: consumes st.A = solve(rr-1). Runs BEFORE stage1<I>
// overwrites ring slot I (which holds raw row rr-5 = the output row's guidance).
template <int I, bool V2SUB, bool OUT>
__device__ __forceinline__ void stage2(St& st, const Ctx& cx, int rr) {
    float hv[12];
    hv[0] = hsum5(st.A[0]); hv[1]  = hsum5(st.A[1]); hv[2]  = hsum5(st.A[2]);
    hv[3] = hsum5(st.A[3]); hv[4]  = hsum5(st.A[4]); hv[5]  = hsum5(st.A[5]);
    hv[6] = hsum5(st.A[6]); hv[7]  = hsum5(st.A[7]); hv[8]  = hsum5(st.A[8]);
    hv[9] = hsum5(st.A[9]); hv[10] = hsum5(st.A[10]); hv[11] = hsum5(st.A[11]);

#pragma unroll
    for (int c = 0; c < 12; ++c) {
        st.V2[c] += hv[c];
        if constexpr (V2SUB) st.V2[c] -= st.r2[I][c];  // read old before overwrite
        st.r2[I][c] = hv[c];
    }

    if constexpr (OUT) {
        // output row yo = yb + rr - 9 == raw row rr-5 (interior, refl identity),
        // live in ring slot I (not yet overwritten this iteration). Needed col
        // xbase+l+2 = raw col of lane l+4 -> row_shl:4 within the 16-lane segment;
        // lanes l>=8 get garbage/0 but have wr==false.
        float gg0 = shlN<4>(st.r1[I][0]);
        float gg1 = shlN<4>(st.r1[I][1]);
        float gg2 = shlN<4>(st.r1[I][2]);
        const int oOff = (cx.yb + rr - 9) * WW + cx.xs;
        // mean = V2 / 25
        float M[12];
#pragma unroll
        for (int c = 0; c < 12; ++c) M[c] = st.V2[c] * 0.04f;
        float o0 = gg0 * M[0] + gg1 * M[3] + gg2 * M[6] + M[9];
        float o1 = gg0 * M[1] + gg1 * M[4] + gg2 * M[7] + M[10];
        float o2 = gg0 * M[2] + gg1 * M[5] + gg2 * M[8] + M[11];
        if (cx.wr) {
            cx.o0[oOff] = o0;
            cx.o1[oOff] = o1;
            cx.o2[oOff] = o2;
        }
    }
}

// Stage 1 of iteration rr: raw-row consume + V1 roll + (solve -> st.A).
// Ring slot = constexpr I (rr%5 == I). Overwrites r1[I] at its end.
template <int I, bool SUB1, bool SOLVE, bool PF>
__device__ __forceinline__ void stage1(St& st, const Ctx& cx, int rr) {
    // capture current values from prefetch buffer BEFORE overwriting it
    float c0 = st.P[0], c1 = st.P[1], c2 = st.P[2];
    float c3 = st.P[3], c4 = st.P[4], c5 = st.P[5];

    if constexpr (PF) {   // next raw row; first use is next iteration.
        const int yn = refl(cx.yb - 4 + rr + 1, HH);
        const int offn = yn * WW + cx.xr;
        st.P[0] = cx.g0[offn]; st.P[1] = cx.g1[offn]; st.P[2] = cx.g2[offn];
        st.P[3] = cx.p0[offn]; st.P[4] = cx.p1[offn]; st.P[5] = cx.p2[offn];
    }

    // add current raw row
    st.V1[0] += c0; st.V1[1] += c1; st.V1[2] += c2;
    st.V1[3] += c3; st.V1[4] += c4; st.V1[5] += c5;
    st.V1[6]  += c0 * c0; st.V1[7]  += c0 * c1; st.V1[8]  += c0 * c2;
    st.V1[9]  += c1 * c1; st.V1[10] += c1 * c2; st.V1[11] += c2 * c2;
    st.V1[12] += c0 * c3; st.V1[13] += c0 * c4; st.V1[14] += c0 * c5;
    st.V1[15] += c1 * c3; st.V1[16] += c1 * c4; st.V1[17] += c1 * c5;
    st.V1[18] += c2 * c3; st.V1[19] += c2 * c4; st.V1[20] += c2 * c5;

    if constexpr (SUB1) {   // drop raw row rr-5 (same constexpr slot I)
        float o0 = st.r1[I][0], o1 = st.r1[I][1], o2 = st.r1[I][2];
        float o3 = st.r1[I][3], o4 = st.r1[I][4], o5 = st.r1[I][5];
        st.V1[0] -= o0; st.V1[1] -= o1; st.V1[2] -= o2;
        st.V1[3] -= o3; st.V1[4] -= o4; st.V1[5] -= o5;
        st.V1[6]  -= o0 * o0; st.V1[7]  -= o0 * o1; st.V1[8]  -= o0 * o2;
        st.V1[9]  -= o1 * o1; st.V1[10] -= o1 * o2; st.V1[11] -= o2 * o2;
        st.V1[12] -= o0 * o3; st.V1[13] -= o0 * o4; st.V1[14] -= o0 * o5;
        st.V1[15] -= o1 * o3; st.V1[16] -= o1 * o4; st.V1[17] -= o1 * o5;
        st.V1[18] -= o2 * o3; st.V1[19] -= o2 * o4; st.V1[20] -= o2 * o5;
    }
    st.r1[I][0] = c0; st.r1[I][1] = c1; st.r1[I][2] = c2;
    st.r1[I][3] = c3; st.r1[I][4] = c4; st.r1[I][5] = c5;

    if constexpr (SOLVE) {
        // ---- stage 1 finalize: a-row at y = yb + rr - 6, a-col xbase+l ----
        float S[21];
#pragma unroll
        for (int c = 0; c < 21; ++c) S[c] = hsum5(st.V1[c]);

        const float nrm = 0.04f;  // 1/25
        float mI0 = S[0] * nrm, mI1 = S[1] * nrm, mI2 = S[2] * nrm;
        float mP0 = S[3] * nrm, mP1 = S[4] * nrm, mP2 = S[5] * nrm;
        float v00 = S[6]  * nrm - mI0 * mI0 + GEPS;
        float v01 = S[7]  * nrm - mI0 * mI1;
        float v02 = S[8]  * nrm - mI0 * mI2;
        float v11 = S[9]  * nrm - mI1 * mI1 + GEPS;
        float v12 = S[10] * nrm - mI1 * mI2;
        float v22 = S[11] * nrm - mI2 * mI2 + GEPS;
        float c00 = S[12] * nrm - mI0 * mP0;
        float c01 = S[13] * nrm - mI0 * mP1;
        float c02 = S[14] * nrm - mI0 * mP2;
        float c10 = S[15] * nrm - mI1 * mP0;
        float c11 = S[16] * nrm - mI1 * mP1;
        float c12 = S[17] * nrm - mI1 * mP2;
        float c20 = S[18] * nrm - mI2 * mP0;
        float c21 = S[19] * nrm - mI2 * mP1;
        float c22 = S[20] * nrm - mI2 * mP2;
        // symmetric 3x3 inverse via adjugate (A PD: PSD + eps*I)
        float i00 = v11 * v22 - v12 * v12;
        float i01 = v02 * v12 - v01 * v22;
        float i02 = v01 * v12 - v02 * v11;
        float i11 = v00 * v22 - v02 * v02;
        float i12 = v01 * v02 - v00 * v12;
        float i22 = v00 * v11 - v01 * v01;
        float det = v00 * i00 + v01 * i01 + v02 * i02;
        float rd  = __builtin_amdgcn_rcpf(det);   // ~1e-7 rel err, fine vs 0.019 threshold
        st.A[0]  = (i00 * c00 + i01 * c10 + i02 * c20) * rd;   // a00
        st.A[1]  = (i00 * c01 + i01 * c11 + i02 * c21) * rd;   // a01
        st.A[2]  = (i00 * c02 + i01 * c12 + i02 * c22) * rd;   // a02
        st.A[3]  = (i01 * c00 + i11 * c10 + i12 * c20) * rd;   // a10
        st.A[4]  = (i01 * c01 + i11 * c11 + i12 * c21) * rd;   // a11
        st.A[5]  = (i01 * c02 + i11 * c12 + i12 * c22) * rd;   // a12
        st.A[6]  = (i02 * c00 + i12 * c10 + i22 * c20) * rd;   // a20
        st.A[7]  = (i02 * c01 + i12 * c11 + i22 * c21) * rd;   // a21
        st.A[8]  = (i02 * c02 + i12 * c12 + i22 * c22) * rd;   // a22
        st.A[9]  = mP0 - (st.A[0] * mI0 + st.A[3] * mI1 + st.A[6] * mI2);  // b0
        st.A[10] = mP1 - (st.A[1] * mI0 + st.A[4] * mI1 + st.A[7] * mI2);  // b1
        st.A[11] = mP2 - (st.A[2] * mI0 + st.A[5] * mI1 + st.A[8] * mI2);  // b2
    }
}

__global__ __launch_bounds__(64, 2) void fused_kernel(
        const float* __restrict__ g, const float* __restrict__ p,
        float* __restrict__ out) {
    const int lane = threadIdx.x;       // 64 threads = 1 wave
    const int l    = lane & 15;
    const int seg  = lane >> 4;
    const int XO   = blockIdx.x * OUTW;
    const int bb   = blockIdx.z;

    const int xbase = XO + seg * SEGW - 2;          // a-col of row-local lane 0
    const int xrq   = xbase + l - 2;                // raw read col (pre-reflect)
    const int xo    = xbase + l + 2;                // output col (valid l < SEGW)

    Ctx cx;
    cx.g0 = g + (size_t)bb * 3 * CSZ; cx.g1 = cx.g0 + CSZ; cx.g2 = cx.g0 + 2 * CSZ;
    cx.p0 = p + (size_t)bb * 3 * CSZ; cx.p1 = cx.p0 + CSZ; cx.p2 = cx.p0 + 2 * CSZ;
    cx.o0 = out + (size_t)bb * 3 * CSZ; cx.o1 = cx.o0 + CSZ; cx.o2 = cx.o0 + 2 * CSZ;
    cx.yb = blockIdx.y * SR;
    cx.xr = refl(xrq, WW);
    cx.xs = (xo < WW) ? xo : (WW - 1);
    cx.wr = (l < SEGW);                             // xo < 512 guaranteed for l < SEGW

    St st;
#pragma unroll
    for (int i = 0; i < 21; ++i) st.V1[i] = 0.f;
#pragma unroll
    for (int i = 0; i < 12; ++i) st.V2[i] = 0.f;
    // A first read at rr=5 stage2 (written rr=4 solve); r1/r2 write-before-read.

    // prime the prefetch buffer with raw row 0
    {
        const int y0 = refl(cx.yb - 4, HH);
        const int off0 = y0 * WW + cx.xr;
        st.P[0] = cx.g0[off0]; st.P[1] = cx.g1[off0]; st.P[2] = cx.g2[off0];
        st.P[3] = cx.p0[off0]; st.P[4] = cx.p1[off0]; st.P[5] = cx.p2[off0];
    }

    // 41 iterations: rr=0..39 consume raw rows; rr=40 = stage2 epilogue.
    // stage2(rr) processes solve(rr-1); outputs at rr=9..40 -> rows yb..yb+31.
    // trip 0: rr 0..4 — stats only; first solve at rr=4
    stage1<0, false, false, true>(st, cx, 0);
    stage1<1, false, false, true>(st, cx, 1);
    stage1<2, false, false, true>(st, cx, 2);
    stage1<3, false, false, true>(st, cx, 3);
    stage1<4, false, true,  true>(st, cx, 4);
    // trip 1: rr 5..9 — stage2 on (V2 accumulate); first OUT at rr=9
    stage2<0, false, false>(st, cx, 5); stage1<0, true, true, true>(st, cx, 5);
    stage2<1, false, false>(st, cx, 6); stage1<1, true, true, true>(st, cx, 6);
    stage2<2, false, false>(st, cx, 7); stage1<2, true, true, true>(st, cx, 7);
    stage2<3, false, false>(st, cx, 8); stage1<3, true, true, true>(st, cx, 8);
    stage2<4, false, true >(st, cx, 9); stage1<4, true, true, true>(st, cx, 9);
    // steady trips: rr 10..39 (PF at rr=39 loads row 40 -> refl 506, in-bounds, unused)
#pragma unroll 1
    for (int t = 2; t <= 7; ++t) {
        const int rrb = 5 * t;
        stage2<0, true, true>(st, cx, rrb + 0); stage1<0, true, true, true>(st, cx, rrb + 0);
        stage2<1, true, true>(st, cx, rrb + 1); stage1<1, true, true, true>(st, cx, rrb + 1);
        stage2<2, true, true>(st, cx, rrb + 2); stage1<2, true, true, true>(st, cx, rrb + 2);
        stage2<3, true, true>(st, cx, rrb + 3); stage1<3, true, true, true>(st, cx, rrb + 3);
        stage2<4, true, true>(st, cx, rrb + 4); stage1<4, true, true, true>(st, cx, rrb + 4);
    }
    // epilogue: stage2 of solve(39); output row yb+31; slot 0 holds raw row 35.
    stage2<0, true, true>(st, cx, 40);
}

}  // namespace

extern "C" void kernel_launch(void* const* d_in, const int* in_sizes, int n_in,
                              void* d_out, int out_size, void* d_ws, size_t ws_size,
                              hipStream_t stream) {
    const float* g  = (const float*)d_in[0];   // guidance [8,3,512,512]
    const float* p  = (const float*)d_in[1];   // input    [8,3,512,512]
    float* out = (float*)d_out;                // [8,3,512,512]

    dim3 grid(WW / OUTW, HH / SR, BN);         // (16, 16, 8) = 2048 single-wave blocks
    dim3 block(64);

    hipLaunchKernelGGL(fused_kernel, grid, block, 0, stream, g, p, out);
}